// Round 1
// baseline (144.374 us; speedup 1.0000x reference)
//
#include <hip/hip_runtime.h>
#include <hip/hip_bf16.h>

#define B_ 32
#define T_ 4096
#define H_ 512
#define TILE_T 4
#define M_TILE 128   // TILE_T * B_
#define BK 64
#define KSTEPS 8     // H_ / BK
#define NTHREADS 512

typedef __attribute__((ext_vector_type(8))) short short8;
typedef __attribute__((ext_vector_type(8))) __bf16 bf16x8;
typedef __attribute__((ext_vector_type(4))) float f32x4;

__device__ __forceinline__ short f2bf(float f) {
    unsigned u = __builtin_bit_cast(unsigned, f);
    u = (u + 0x7fffu + ((u >> 16) & 1u)) >> 16;
    return (short)u;
}

// ---------------- prep: W2 -> bf16, pre-swizzled per K-step ----------------
// w2p[s][h][kp] = bf16( W[h][512 + s*64 + (kp ^ ((h&7)<<3))] )
__global__ void prep_w2(const float* __restrict__ W, short* __restrict__ w2p) {
    int idx = blockIdx.x * 256 + threadIdx.x;   // 0 .. 262143
    int kp = idx & 63;
    int h  = (idx >> 6) & 511;
    int s  = idx >> 15;
    int k  = kp ^ ((h & 7) << 3);
    w2p[idx] = f2bf(W[h * (2 * H_) + H_ + s * BK + k]);
}

// ---------------- prep: hid_proj[b][h] = hidden[b,:]*W1[h,:] + bias[h] (f32 exact) ----
__global__ void prep_hid(const float* __restrict__ hidden,
                         const float* __restrict__ W,
                         const float* __restrict__ bias,
                         float* __restrict__ hidproj) {
    __shared__ float hrow[H_];
    int b = blockIdx.y;
    int h = blockIdx.x * 128 + threadIdx.x;
    for (int i = threadIdx.x; i < H_; i += 128) hrow[i] = hidden[b * H_ + i];
    __syncthreads();
    const float* wr = W + (size_t)h * (2 * H_);
    float acc = bias[h];
#pragma unroll 4
    for (int k = 0; k < H_; k += 4) {
        acc += hrow[k]     * wr[k];
        acc += hrow[k + 1] * wr[k + 1];
        acc += hrow[k + 2] * wr[k + 2];
        acc += hrow[k + 3] * wr[k + 3];
    }
    hidproj[b * H_ + h] = acc;
}

// ---------------- main fused kernel ----------------
// grid: T_/TILE_T blocks; block: 512 threads (8 waves), wave w owns h in [w*64, w*64+64)
__global__ __launch_bounds__(NTHREADS, 2)
void attn_main(const float* __restrict__ enc,      // [T][B][H] f32
               const float* __restrict__ hidproj,  // [B][H] f32
               const short* __restrict__ w2p,      // [KSTEPS][H][BK] bf16 pre-swizzled
               const float* __restrict__ vvec,     // [H]
               float* __restrict__ out)            // [B][T]
{
    __shared__ __align__(16) short lds_a[M_TILE * BK];  // 16 KB
    __shared__ __align__(16) short lds_w[H_ * BK];      // 64 KB

    const int tid  = threadIdx.x;
    const int lane = tid & 63;
    const int wid  = tid >> 6;
    const int t0   = blockIdx.x * TILE_T;
    const int n0   = wid * 64;
    const int lo   = lane & 15;
    const int hi4  = lane >> 4;

    f32x4 acc[8][4];
#pragma unroll
    for (int i = 0; i < 8; ++i)
#pragma unroll
        for (int j = 0; j < 4; ++j) acc[i][j] = f32x4{0.f, 0.f, 0.f, 0.f};

    const int s0row = tid >> 3;   // A-staging: rows 0..63 (seg0), +64 (seg1)
    const int s0ks  = tid & 7;
    const float* encbase = enc + (size_t)(t0 * B_) * H_;

    for (int kk = 0; kk < KSTEPS; ++kk) {
        // ---- stage W via global_load_lds (linear dest; swizzle baked into source) ----
        const short* wsrc = w2p + (size_t)kk * (H_ * BK);
#pragma unroll
        for (int r = 0; r < 8; ++r) {
            __builtin_amdgcn_global_load_lds(
                (const __attribute__((address_space(1))) void*)(wsrc + (r * 512 + tid) * 8),
                (__attribute__((address_space(3))) void*)(lds_w + (r * 512 + wid * 64) * 8),
                16, 0, 0);
        }
        // ---- stage A: reg-load f32, cvt bf16, swizzled ds_write_b128 ----
#pragma unroll
        for (int si = 0; si < 2; ++si) {
            int row = s0row + si * 64;
            const float* src = encbase + (size_t)row * H_ + kk * BK + s0ks * 8;
            f32x4 x0 = *(const f32x4*)(src);
            f32x4 x1 = *(const f32x4*)(src + 4);
            short8 pk;
            pk[0] = f2bf(x0[0]); pk[1] = f2bf(x0[1]); pk[2] = f2bf(x0[2]); pk[3] = f2bf(x0[3]);
            pk[4] = f2bf(x1[0]); pk[5] = f2bf(x1[1]); pk[6] = f2bf(x1[2]); pk[7] = f2bf(x1[3]);
            int kp = (s0ks ^ (row & 7)) * 8;
            *(short8*)&lds_a[row * BK + kp] = pk;
        }
        __syncthreads();

        // ---- compute: 2 k-subsets of 32, 8 M-frags x 4 N-frags ----
#pragma unroll
        for (int ks = 0; ks < 2; ++ks) {
            bf16x8 bfrag[4];
            int kbase = ks * 32 + hi4 * 8;
#pragma unroll
            for (int ni = 0; ni < 4; ++ni) {
                int hrow = n0 + ni * 16 + lo;
                int kp = kbase ^ ((hrow & 7) << 3);
                bfrag[ni] = *(const bf16x8*)&lds_w[hrow * BK + kp];
            }
#pragma unroll
            for (int mi = 0; mi < 8; ++mi) {
                int arow = mi * 16 + lo;
                int kp = kbase ^ ((arow & 7) << 3);
                bf16x8 afrag = *(const bf16x8*)&lds_a[arow * BK + kp];
#pragma unroll
                for (int ni = 0; ni < 4; ++ni)
                    acc[mi][ni] = __builtin_amdgcn_mfma_f32_16x16x32_bf16(
                        afrag, bfrag[ni], acc[mi][ni], 0, 0, 0);
            }
        }
        __syncthreads();
    }

    // ---- epilogue ----
    // lane holds: (mi,j) -> Mrow = mi*16 + hi4*4 + j ; (ni) -> h = n0 + ni*16 + lo
    {
        float hp[2][4][4];
#pragma unroll
        for (int par = 0; par < 2; ++par)
#pragma unroll
            for (int j = 0; j < 4; ++j) {
                int b = par * 16 + hi4 * 4 + j;
#pragma unroll
                for (int ni = 0; ni < 4; ++ni)
                    hp[par][j][ni] = hidproj[b * H_ + n0 + ni * 16 + lo];
            }
#pragma unroll
        for (int mi = 0; mi < 8; ++mi)
#pragma unroll
            for (int ni = 0; ni < 4; ++ni)
#pragma unroll
                for (int j = 0; j < 4; ++j)
                    acc[mi][ni][j] += hp[mi & 1][j][ni];
    }

    float vh[4];
#pragma unroll
    for (int ni = 0; ni < 4; ++ni) vh[ni] = vvec[n0 + ni * 16 + lo];

    float scp[8][4];  // [mi][j] partial scores (summed over this lane's 4 h)
#pragma unroll
    for (int tl = 0; tl < 4; ++tl) {
        const int m0 = tl * 2, m1 = tl * 2 + 1;
#pragma unroll
        for (int ni = 0; ni < 4; ++ni) {
            float mx = -1e30f;
#pragma unroll
            for (int j = 0; j < 4; ++j) {
                mx = fmaxf(mx, acc[m0][ni][j]);
                mx = fmaxf(mx, acc[m1][ni][j]);
            }
            mx = fmaxf(mx, __shfl_xor(mx, 16));
            mx = fmaxf(mx, __shfl_xor(mx, 32));
            float e0[4], e1[4];
            float sum = 0.f;
#pragma unroll
            for (int j = 0; j < 4; ++j) {
                e0[j] = __expf(acc[m0][ni][j] - mx);
                e1[j] = __expf(acc[m1][ni][j] - mx);
                sum += e0[j] + e1[j];
            }
            sum += __shfl_xor(sum, 16);
            sum += __shfl_xor(sum, 32);
            float rs = vh[ni] / sum;  // fold v[h] and 1/denom
#pragma unroll
            for (int j = 0; j < 4; ++j) {
                if (ni == 0) { scp[m0][j] = e0[j] * rs; scp[m1][j] = e1[j] * rs; }
                else         { scp[m0][j] += e0[j] * rs; scp[m1][j] += e1[j] * rs; }
            }
        }
    }

    // reduce over the 16 lanes (lo) that hold different h for the same Mrow
#pragma unroll
    for (int mi = 0; mi < 8; ++mi)
#pragma unroll
        for (int j = 0; j < 4; ++j) {
            float x = scp[mi][j];
            x += __shfl_xor(x, 1);
            x += __shfl_xor(x, 2);
            x += __shfl_xor(x, 4);
            x += __shfl_xor(x, 8);
            scp[mi][j] = x;
        }

    // cross-wave reduce via LDS (reuse lds_a)
    float* red = (float*)lds_a;  // [8][128] = 4 KB
    if (lo == 0) {
#pragma unroll
        for (int mi = 0; mi < 8; ++mi)
#pragma unroll
            for (int j = 0; j < 4; ++j)
                red[wid * 128 + mi * 16 + hi4 * 4 + j] = scp[mi][j];
    }
    __syncthreads();
    if (tid < 128) {
        float s = 0.f;
#pragma unroll
        for (int w = 0; w < 8; ++w) s += red[w * 128 + tid];
        int b  = tid & 31;
        int tl = tid >> 5;
        out[(size_t)b * T_ + (t0 + tl)] = fmaxf(s, 0.f);
    }
}

extern "C" void kernel_launch(void* const* d_in, const int* in_sizes, int n_in,
                              void* d_out, int out_size, void* d_ws, size_t ws_size,
                              hipStream_t stream) {
    const float* hidden = (const float*)d_in[0];
    const float* enc    = (const float*)d_in[1];
    const float* W      = (const float*)d_in[2];
    const float* bias   = (const float*)d_in[3];
    const float* v      = (const float*)d_in[4];
    float* out = (float*)d_out;

    float* hidproj = (float*)d_ws;                    // 64 KB
    short* w2p     = (short*)((char*)d_ws + 65536);   // 512 KB

    prep_w2<<<1024, 256, 0, stream>>>(W, w2p);
    prep_hid<<<dim3(4, 32), 128, 0, stream>>>(hidden, W, bias, hidproj);
    attn_main<<<T_ / TILE_T, NTHREADS, 0, stream>>>(enc, hidproj, w2p, v, out);
}